// Round 1
// baseline (548.460 us; speedup 1.0000x reference)
//
#include <hip/hip_runtime.h>

#define NN 50000
#define NE 800000
#define KC 512
#define OC 256  // 128 mu cols + 128 logstd cols, fused

// ---------------- degree count ----------------
__global__ __launch_bounds__(256) void count_deg_kernel(const int* __restrict__ ei,
                                                        int* __restrict__ deg) {
    int e = blockIdx.x * 256 + threadIdx.x;
    if (e < NE) atomicAdd(&deg[ei[NE + e]], 1);
}

// ---------------- exclusive scan (single block) + dinv ----------------
__global__ __launch_bounds__(1024) void scan_kernel(const int* __restrict__ deg,
                                                    int* __restrict__ row_start,
                                                    int* __restrict__ cursor,
                                                    float* __restrict__ dinv) {
    __shared__ int lds[1024];
    const int CHUNK = (NN + 1023) / 1024;  // 49
    int tid = threadIdx.x;
    int base = tid * CHUNK;
    int s = 0;
    for (int i = 0; i < CHUNK; ++i) {
        int idx = base + i;
        if (idx < NN) s += deg[idx];
    }
    lds[tid] = s;
    __syncthreads();
    // Hillis-Steele inclusive scan
    for (int off = 1; off < 1024; off <<= 1) {
        int v = 0;
        if (tid >= off) v = lds[tid - off];
        __syncthreads();
        lds[tid] += v;
        __syncthreads();
    }
    int run = (tid == 0) ? 0 : lds[tid - 1];  // exclusive prefix of this chunk
    for (int i = 0; i < CHUNK; ++i) {
        int idx = base + i;
        if (idx < NN) {
            int d = deg[idx];
            row_start[idx] = run;
            cursor[idx] = run;
            dinv[idx] = rsqrtf((float)(d + 1));  // +1 self-loop
            run += d;
        }
    }
    if (tid == 1023) row_start[NN] = lds[1023];
}

// ---------------- scatter edges into CSR (by dst) ----------------
__global__ __launch_bounds__(256) void scatter_kernel(const int* __restrict__ ei,
                                                      int* __restrict__ cursor,
                                                      int* __restrict__ csr_src) {
    int e = blockIdx.x * 256 + threadIdx.x;
    if (e < NE) {
        int d = ei[NE + e];
        int pos = atomicAdd(&cursor[d], 1);
        csr_src[pos] = ei[e];
    }
}

// ---------------- fused GEMM: h[N][256] = x[N][512] @ [Wmu | Wls] ----------------
__global__ __launch_bounds__(256) void gemm_kernel(const float* __restrict__ x,
                                                   const float* __restrict__ Wmu,
                                                   const float* __restrict__ Wls,
                                                   float* __restrict__ h) {
    __shared__ float xs[32 * 32];   // [k][row]
    __shared__ float ws[32 * 256];  // [k][col]
    int tid = threadIdx.x;
    int r0 = blockIdx.x * 32;
    int tx = tid & 63;   // col group: cols tx*4 .. tx*4+3
    int w = tid >> 6;    // wave -> rows w*8 .. w*8+7

    float acc[8][4];
#pragma unroll
    for (int m = 0; m < 8; ++m)
#pragma unroll
        for (int j = 0; j < 4; ++j) acc[m][j] = 0.0f;

    for (int kb = 0; kb < KC; kb += 32) {
        // stage x tile (transposed into [k][row])
        {
            int row = tid >> 3;  // 0..31
            int kq = tid & 7;    // 0..7
            int rr = r0 + row;
            if (rr > NN - 1) rr = NN - 1;
            const float4 v = *(const float4*)&x[(size_t)rr * KC + kb + kq * 4];
            xs[(kq * 4 + 0) * 32 + row] = v.x;
            xs[(kq * 4 + 1) * 32 + row] = v.y;
            xs[(kq * 4 + 2) * 32 + row] = v.z;
            xs[(kq * 4 + 3) * 32 + row] = v.w;
        }
        // stage W tile [32][256]
#pragma unroll
        for (int i = 0; i < 8; ++i) {
            int f = tid + i * 256;     // 0..2047
            int kk = f >> 6;           // 0..31
            int c = (f & 63) * 4;      // 0..252
            float4 v;
            if (c < 128)
                v = *(const float4*)&Wmu[(size_t)(kb + kk) * 128 + c];
            else
                v = *(const float4*)&Wls[(size_t)(kb + kk) * 128 + (c - 128)];
            *(float4*)&ws[kk * 256 + c] = v;
        }
        __syncthreads();

#pragma unroll 4
        for (int k = 0; k < 32; ++k) {
            float4 wv = *(float4*)&ws[k * 256 + tx * 4];
            float4 xa = *(float4*)&xs[k * 32 + w * 8];
            float4 xb = *(float4*)&xs[k * 32 + w * 8 + 4];
            float xm[8] = {xa.x, xa.y, xa.z, xa.w, xb.x, xb.y, xb.z, xb.w};
            float wj[4] = {wv.x, wv.y, wv.z, wv.w};
#pragma unroll
            for (int m = 0; m < 8; ++m)
#pragma unroll
                for (int j = 0; j < 4; ++j) acc[m][j] += xm[m] * wj[j];
        }
        __syncthreads();
    }
    // store h
#pragma unroll
    for (int m = 0; m < 8; ++m) {
        int row = r0 + w * 8 + m;
        if (row < NN) {
            float4 v = {acc[m][0], acc[m][1], acc[m][2], acc[m][3]};
            *(float4*)&h[(size_t)row * OC + tx * 4] = v;
        }
    }
}

// ---------------- aggregation: out = dinv[n]*(sum h[s]*dinv[s] + h[n]*dinv[n]) + b ----------------
__global__ __launch_bounds__(256) void aggregate_kernel(const float* __restrict__ h,
                                                        const int* __restrict__ row_start,
                                                        const int* __restrict__ csr_src,
                                                        const float* __restrict__ dinv,
                                                        const float* __restrict__ bmu,
                                                        const float* __restrict__ bls,
                                                        float* __restrict__ out) {
    int tid = threadIdx.x;
    int lane = tid & 63;
    int node = blockIdx.x * 4 + (tid >> 6);

    const float4* h4 = (const float4*)h;
    float dn = dinv[node];
    float4 a = h4[(size_t)node * 64 + lane];  // self-loop term
    float4 acc;
    acc.x = a.x * dn;
    acc.y = a.y * dn;
    acc.z = a.z * dn;
    acc.w = a.w * dn;

    int rs = row_start[node];
    int re = row_start[node + 1];
    for (int e = rs; e < re; ++e) {
        int s = csr_src[e];
        float f = dinv[s];
        float4 v = h4[(size_t)s * 64 + lane];
        acc.x += v.x * f;
        acc.y += v.y * f;
        acc.z += v.z * f;
        acc.w += v.w * f;
    }
    acc.x *= dn;
    acc.y *= dn;
    acc.z *= dn;
    acc.w *= dn;

    float4* out4 = (float4*)out;
    if (lane < 32) {
        float4 b = ((const float4*)bmu)[lane];
        float4 r = {acc.x + b.x, acc.y + b.y, acc.z + b.z, acc.w + b.w};
        out4[(size_t)node * 32 + lane] = r;
    } else {
        float4 b = ((const float4*)bls)[lane - 32];
        float4 r = {acc.x + b.x, acc.y + b.y, acc.z + b.z, acc.w + b.w};
        out4[(size_t)NN * 32 + (size_t)node * 32 + (lane - 32)] = r;
    }
}

extern "C" void kernel_launch(void* const* d_in, const int* in_sizes, int n_in,
                              void* d_out, int out_size, void* d_ws, size_t ws_size,
                              hipStream_t stream) {
    const float* x = (const float*)d_in[0];
    const int* ei = (const int*)d_in[1];  // [2][NE]: src then dst
    const float* Wmu = (const float*)d_in[2];
    const float* bmu = (const float*)d_in[3];
    const float* Wls = (const float*)d_in[4];
    const float* bls = (const float*)d_in[5];
    float* out = (float*)d_out;

    char* ws = (char*)d_ws;
    size_t off = 0;
    auto alloc = [&](size_t bytes) {
        void* p = ws + off;
        off += (bytes + 255) & ~(size_t)255;
        return p;
    };
    float* h = (float*)alloc((size_t)NN * OC * sizeof(float));       // 51.2 MB
    int* deg = (int*)alloc((size_t)NN * sizeof(int));
    int* row_start = (int*)alloc((size_t)(NN + 1) * sizeof(int));
    int* cursor = (int*)alloc((size_t)NN * sizeof(int));
    int* csr_src = (int*)alloc((size_t)NE * sizeof(int));
    float* dinv = (float*)alloc((size_t)NN * sizeof(float));

    hipMemsetAsync(deg, 0, (size_t)NN * sizeof(int), stream);

    count_deg_kernel<<<(NE + 255) / 256, 256, 0, stream>>>(ei, deg);
    scan_kernel<<<1, 1024, 0, stream>>>(deg, row_start, cursor, dinv);
    scatter_kernel<<<(NE + 255) / 256, 256, 0, stream>>>(ei, cursor, csr_src);
    gemm_kernel<<<(NN + 31) / 32, 256, 0, stream>>>(x, Wmu, Wls, h);
    aggregate_kernel<<<NN / 4, 256, 0, stream>>>(h, row_start, csr_src, dinv, bmu, bls, out);
}

// Round 2
// 353.052 us; speedup vs baseline: 1.5535x; 1.5535x over previous
//
#include <hip/hip_runtime.h>

#define NN 50000
#define NE 800000
#define KC 512
#define OC 256  // 128 mu cols | 128 logstd cols

typedef float f32x4 __attribute__((ext_vector_type(4)));
typedef short bf16x8 __attribute__((ext_vector_type(8)));

__device__ __forceinline__ unsigned f2bf(float f) {
    union { float f; unsigned u; } v; v.f = f;
    return (v.u + 0x7FFFu + ((v.u >> 16) & 1u)) >> 16;  // RNE
}
__device__ __forceinline__ float bf2f(unsigned short b) {
    union { unsigned u; float f; } v; v.u = ((unsigned)b) << 16;
    return v.f;
}

// ---------------- degree count ----------------
__global__ __launch_bounds__(256) void count_deg_kernel(const int* __restrict__ ei,
                                                        int* __restrict__ deg) {
    int e = blockIdx.x * 256 + threadIdx.x;
    if (e < NE) atomicAdd(&deg[ei[NE + e]], 1);
}

// ---------------- exclusive scan (single block) + dinv ----------------
__global__ __launch_bounds__(1024) void scan_kernel(const int* __restrict__ deg,
                                                    int* __restrict__ row_start,
                                                    int* __restrict__ cursor,
                                                    float* __restrict__ dinv) {
    __shared__ int lds[1024];
    const int CHUNK = (NN + 1023) / 1024;  // 49
    int tid = threadIdx.x;
    int base = tid * CHUNK;
    int s = 0;
    for (int i = 0; i < CHUNK; ++i) {
        int idx = base + i;
        if (idx < NN) s += deg[idx];
    }
    lds[tid] = s;
    __syncthreads();
    for (int off = 1; off < 1024; off <<= 1) {
        int v = 0;
        if (tid >= off) v = lds[tid - off];
        __syncthreads();
        lds[tid] += v;
        __syncthreads();
    }
    int run = (tid == 0) ? 0 : lds[tid - 1];
    for (int i = 0; i < CHUNK; ++i) {
        int idx = base + i;
        if (idx < NN) {
            int d = deg[idx];
            row_start[idx] = run;
            cursor[idx] = run;
            dinv[idx] = rsqrtf((float)(d + 1));  // +1 self-loop
            run += d;
        }
    }
    if (tid == 1023) row_start[NN] = lds[1023];
}

// ---------------- scatter edges into CSR (by dst) ----------------
__global__ __launch_bounds__(256) void scatter_kernel(const int* __restrict__ ei,
                                                      int* __restrict__ cursor,
                                                      int* __restrict__ csr_src) {
    int e = blockIdx.x * 256 + threadIdx.x;
    if (e < NE) {
        int d = ei[NE + e];
        int pos = atomicAdd(&cursor[d], 1);
        csr_src[pos] = ei[e];
    }
}

// ---------------- W -> fused bf16, fragment-slot-ordered + XOR-swizzled ----------------
// Per K-step tile kb (32 k): 1024 slots x 16B. Logical slot s = col*4 + g holds
// Wfused[kb*32 + g*8 + j][col], j=0..7. Physical slot u = s ^ ((s>>3)&7) (involution).
__global__ __launch_bounds__(256) void convw_kernel(const float* __restrict__ Wmu,
                                                    const float* __restrict__ Wls,
                                                    uint4* __restrict__ Wc) {
    int idx = blockIdx.x * 256 + threadIdx.x;  // 16384 slots total
    int u = idx & 1023;
    int kb = idx >> 10;
    int s = u ^ ((u >> 3) & 7);
    int col = s >> 2;
    int g = s & 3;
    int k0 = kb * 32 + g * 8;
    const float* Wsrc = (col < 128) ? (Wmu + col) : (Wls + (col - 128));
    unsigned o[4];
#pragma unroll
    for (int p = 0; p < 4; ++p) {
        float lo = Wsrc[(size_t)(k0 + 2 * p) * 128];
        float hi = Wsrc[(size_t)(k0 + 2 * p + 1) * 128];
        o[p] = f2bf(lo) | (f2bf(hi) << 16);
    }
    uint4 v;
    v.x = o[0]; v.y = o[1]; v.z = o[2]; v.w = o[3];
    Wc[idx] = v;
}

// ---------------- MFMA GEMM: hs[N][256] = bf16(x @ [Wmu|Wls]) * dinv[row] ----------------
// BM=64, BN=256, BK=32, 4 waves; wave w owns cols w*64..w*64+63 (4x4 16x16 frags).
__global__ __launch_bounds__(256) void gemm_kernel(const float* __restrict__ x,
                                                   const uint4* __restrict__ Wc,
                                                   const float* __restrict__ dinv,
                                                   unsigned short* __restrict__ hs) {
    // A: row stride 40 ushort = 80B (odd multiple of 16B -> conflict-free frag reads)
    __shared__ __align__(16) unsigned short As[2][64 * 40];
    __shared__ __align__(16) unsigned short Bs[2][1024 * 8];

    int tid = threadIdx.x;
    int lane = tid & 63;
    int w = tid >> 6;
    int r0 = blockIdx.x * 64;

    // A staging assignment: thread t loads 8 f32 of row (t>>2), k-chunk (t&3)*8
    int st_row = tid >> 2;
    int st_g = tid & 3;
    int xr = r0 + st_row;
    if (xr > NN - 1) xr = NN - 1;
    const float* xg = x + (size_t)xr * KC + st_g * 8;

    f32x4 acc[4][4];
    f32x4 zz = {0.f, 0.f, 0.f, 0.f};
#pragma unroll
    for (int a = 0; a < 4; ++a)
#pragma unroll
        for (int b = 0; b < 4; ++b) acc[a][b] = zz;

    float4 a0, a1;
    uint4 b0, b1, b2, b3;

    auto loadAB = [&](int kb) {
        a0 = *(const float4*)(xg + kb * 32);
        a1 = *(const float4*)(xg + kb * 32 + 4);
        const uint4* wsrc = Wc + kb * 1024 + tid;
        b0 = wsrc[0];
        b1 = wsrc[256];
        b2 = wsrc[512];
        b3 = wsrc[768];
    };
    auto storeAB = [&](int buf) {
        uint4 av;
        av.x = f2bf(a0.x) | (f2bf(a0.y) << 16);
        av.y = f2bf(a0.z) | (f2bf(a0.w) << 16);
        av.z = f2bf(a1.x) | (f2bf(a1.y) << 16);
        av.w = f2bf(a1.z) | (f2bf(a1.w) << 16);
        *(uint4*)&As[buf][st_row * 40 + st_g * 8] = av;
        uint4* bd = (uint4*)&Bs[buf][0];
        bd[tid] = b0;
        bd[tid + 256] = b1;
        bd[tid + 512] = b2;
        bd[tid + 768] = b3;
    };

    int i16 = lane & 15;
    int g4 = lane >> 4;

    loadAB(0);
    storeAB(0);
    __syncthreads();

#pragma unroll 2
    for (int kb = 0; kb < 16; ++kb) {
        int buf = kb & 1;
        if (kb < 15) loadAB(kb + 1);

        bf16x8 af[4];
#pragma unroll
        for (int fr = 0; fr < 4; ++fr)
            af[fr] = *(const bf16x8*)&As[buf][(fr * 16 + i16) * 40 + g4 * 8];
#pragma unroll
        for (int fc = 0; fc < 4; ++fc) {
            int scol = ((w * 64 + fc * 16 + i16) << 2) + g4;
            int u = scol ^ ((scol >> 3) & 7);
            bf16x8 bfrag = *(const bf16x8*)&Bs[buf][u * 8];
#pragma unroll
            for (int fr = 0; fr < 4; ++fr)
                acc[fr][fc] = __builtin_amdgcn_mfma_f32_16x16x32_bf16(af[fr], bfrag, acc[fr][fc], 0, 0, 0);
        }

        if (kb < 15) storeAB(buf ^ 1);
        __syncthreads();
    }

    // epilogue: C/D layout col=lane&15, row=(lane>>4)*4+reg (m89-verified); scale by dinv
#pragma unroll
    for (int fr = 0; fr < 4; ++fr) {
#pragma unroll
        for (int r = 0; r < 4; ++r) {
            int gr = r0 + fr * 16 + g4 * 4 + r;
            if (gr < NN) {
                float dv = dinv[gr];
#pragma unroll
                for (int fc = 0; fc < 4; ++fc) {
                    int col = w * 64 + fc * 16 + i16;
                    hs[(size_t)gr * OC + col] = (unsigned short)f2bf(acc[fr][fc][r] * dv);
                }
            }
        }
    }
}

// ---------------- aggregation: out = dinv[n]*(sum_e hs[src] + hs[n]) + b ----------------
__global__ __launch_bounds__(256) void aggregate_kernel(const unsigned short* __restrict__ hs,
                                                        const int* __restrict__ row_start,
                                                        const int* __restrict__ csr_src,
                                                        const float* __restrict__ dinv,
                                                        const float* __restrict__ bmu,
                                                        const float* __restrict__ bls,
                                                        float* __restrict__ out) {
    int tid = threadIdx.x;
    int lane = tid & 63;
    int node = blockIdx.x * 4 + (tid >> 6);

    const unsigned short* hrow = hs + lane * 4;  // lane covers cols 4l..4l+3
    float acc0, acc1, acc2, acc3;
    {
        ushort4 v = *(const ushort4*)&hrow[(size_t)node * OC];
        acc0 = bf2f(v.x);
        acc1 = bf2f(v.y);
        acc2 = bf2f(v.z);
        acc3 = bf2f(v.w);
    }
    int rs = row_start[node], re = row_start[node + 1];
    int e = rs;
    for (; e + 1 < re; e += 2) {
        int s0 = csr_src[e], s1 = csr_src[e + 1];
        ushort4 v0 = *(const ushort4*)&hrow[(size_t)s0 * OC];
        ushort4 v1 = *(const ushort4*)&hrow[(size_t)s1 * OC];
        acc0 += bf2f(v0.x) + bf2f(v1.x);
        acc1 += bf2f(v0.y) + bf2f(v1.y);
        acc2 += bf2f(v0.z) + bf2f(v1.z);
        acc3 += bf2f(v0.w) + bf2f(v1.w);
    }
    if (e < re) {
        int s0 = csr_src[e];
        ushort4 v0 = *(const ushort4*)&hrow[(size_t)s0 * OC];
        acc0 += bf2f(v0.x);
        acc1 += bf2f(v0.y);
        acc2 += bf2f(v0.z);
        acc3 += bf2f(v0.w);
    }
    float dn = dinv[node];
    if (lane < 32) {
        float4 b = ((const float4*)bmu)[lane];
        float4 r = {acc0 * dn + b.x, acc1 * dn + b.y, acc2 * dn + b.z, acc3 * dn + b.w};
        ((float4*)out)[(size_t)node * 32 + lane] = r;
    } else {
        float4 b = ((const float4*)bls)[lane - 32];
        float4 r = {acc0 * dn + b.x, acc1 * dn + b.y, acc2 * dn + b.z, acc3 * dn + b.w};
        ((float4*)out)[(size_t)(NN + node) * 32 + (lane - 32)] = r;
    }
}

extern "C" void kernel_launch(void* const* d_in, const int* in_sizes, int n_in,
                              void* d_out, int out_size, void* d_ws, size_t ws_size,
                              hipStream_t stream) {
    const float* x = (const float*)d_in[0];
    const int* ei = (const int*)d_in[1];  // [2][NE]: src then dst
    const float* Wmu = (const float*)d_in[2];
    const float* bmu = (const float*)d_in[3];
    const float* Wls = (const float*)d_in[4];
    const float* bls = (const float*)d_in[5];
    float* out = (float*)d_out;

    char* ws = (char*)d_ws;
    size_t off = 0;
    auto alloc = [&](size_t bytes) {
        void* p = ws + off;
        off += (bytes + 255) & ~(size_t)255;
        return p;
    };
    unsigned short* hs = (unsigned short*)alloc((size_t)NN * OC * sizeof(unsigned short));  // 25.6 MB
    uint4* Wc = (uint4*)alloc((size_t)16384 * 16);                                          // 256 KB
    int* deg = (int*)alloc((size_t)NN * sizeof(int));
    int* row_start = (int*)alloc((size_t)(NN + 1) * sizeof(int));
    int* cursor = (int*)alloc((size_t)NN * sizeof(int));
    int* csr_src = (int*)alloc((size_t)NE * sizeof(int));
    float* dinv = (float*)alloc((size_t)NN * sizeof(float));

    hipMemsetAsync(deg, 0, (size_t)NN * sizeof(int), stream);

    count_deg_kernel<<<(NE + 255) / 256, 256, 0, stream>>>(ei, deg);
    scan_kernel<<<1, 1024, 0, stream>>>(deg, row_start, cursor, dinv);
    scatter_kernel<<<(NE + 255) / 256, 256, 0, stream>>>(ei, cursor, csr_src);
    convw_kernel<<<64, 256, 0, stream>>>(Wmu, Wls, Wc);
    gemm_kernel<<<(NN + 63) / 64, 256, 0, stream>>>(x, Wc, dinv, hs);
    aggregate_kernel<<<NN / 4, 256, 0, stream>>>(hs, row_start, csr_src, dinv, bmu, bls, out);
}

// Round 3
// 216.559 us; speedup vs baseline: 2.5326x; 1.6303x over previous
//
#include <hip/hip_runtime.h>

#define NN 50000
#define NE 800000
#define KC 512
#define OC 256  // 128 mu cols | 128 logstd cols
#define NB_SCAN 196  // ceil(NN/256)

typedef float f32x4 __attribute__((ext_vector_type(4)));
typedef short bf16x8 __attribute__((ext_vector_type(8)));

__device__ __forceinline__ unsigned f2bf(float f) {
    union { float f; unsigned u; } v; v.f = f;
    return (v.u + 0x7FFFu + ((v.u >> 16) & 1u)) >> 16;  // RNE
}
__device__ __forceinline__ float bf2f(unsigned short b) {
    union { unsigned u; float f; } v; v.u = ((unsigned)b) << 16;
    return v.f;
}

// ---------------- degree count ----------------
__global__ __launch_bounds__(256) void count_deg_kernel(const int* __restrict__ ei,
                                                        int* __restrict__ deg) {
    int e = blockIdx.x * 256 + threadIdx.x;
    if (e < NE) atomicAdd(&deg[ei[NE + e]], 1);
}

// ---------------- hierarchical scan: A) per-block sums ----------------
__global__ __launch_bounds__(256) void scan_part_kernel(const int* __restrict__ deg,
                                                        int* __restrict__ partial) {
    int tid = threadIdx.x;
    int i = blockIdx.x * 256 + tid;
    int v = (i < NN) ? deg[i] : 0;
#pragma unroll
    for (int off = 32; off > 0; off >>= 1) v += __shfl_down(v, off, 64);
    __shared__ int wsum[4];
    if ((tid & 63) == 0) wsum[tid >> 6] = v;
    __syncthreads();
    if (tid == 0) partial[blockIdx.x] = wsum[0] + wsum[1] + wsum[2] + wsum[3];
}

// ---------------- B) scan the 196 partials (one tiny block) ----------------
__global__ __launch_bounds__(256) void scan_block_kernel(const int* __restrict__ partial,
                                                         int* __restrict__ blockoff) {
    __shared__ int lds[256];
    int tid = threadIdx.x;
    int v = (tid < NB_SCAN) ? partial[tid] : 0;
    lds[tid] = v;
    __syncthreads();
    for (int off = 1; off < 256; off <<= 1) {
        int t = (tid >= off) ? lds[tid - off] : 0;
        __syncthreads();
        lds[tid] += t;
        __syncthreads();
    }
    if (tid < NB_SCAN) blockoff[tid] = lds[tid] - v;  // exclusive
}

// ---------------- C) apply: block-local scan + offset, emit CSR ptrs + dinv ----------------
__global__ __launch_bounds__(256) void scan_apply_kernel(const int* __restrict__ deg,
                                                         const int* __restrict__ blockoff,
                                                         int* __restrict__ row_start,
                                                         int* __restrict__ cursor,
                                                         float* __restrict__ dinv) {
    int tid = threadIdx.x;
    int lane = tid & 63;
    int w = tid >> 6;
    int i = blockIdx.x * 256 + tid;
    int d = (i < NN) ? deg[i] : 0;
    int v = d;
#pragma unroll
    for (int off = 1; off < 64; off <<= 1) {
        int t = __shfl_up(v, off, 64);
        if (lane >= off) v += t;
    }
    __shared__ int wsum[4];
    if (lane == 63) wsum[w] = v;
    __syncthreads();
    int wof = 0;
    for (int k = 0; k < w; ++k) wof += wsum[k];
    int excl = blockoff[blockIdx.x] + wof + v - d;
    if (i < NN) {
        row_start[i] = excl;
        cursor[i] = excl;
        dinv[i] = rsqrtf((float)(d + 1));  // +1 self-loop
    }
    if (i == NN - 1) row_start[NN] = excl + d;
}

// ---------------- scatter edges into CSR (by dst) ----------------
__global__ __launch_bounds__(256) void scatter_kernel(const int* __restrict__ ei,
                                                      int* __restrict__ cursor,
                                                      int* __restrict__ csr_src) {
    int e = blockIdx.x * 256 + threadIdx.x;
    if (e < NE) {
        int d = ei[NE + e];
        int pos = atomicAdd(&cursor[d], 1);
        csr_src[pos] = ei[e];
    }
}

// ---------------- W -> fused bf16, fragment-slot-ordered + XOR-swizzled ----------------
__global__ __launch_bounds__(256) void convw_kernel(const float* __restrict__ Wmu,
                                                    const float* __restrict__ Wls,
                                                    uint4* __restrict__ Wc) {
    int idx = blockIdx.x * 256 + threadIdx.x;  // 16384 slots total
    int u = idx & 1023;
    int kb = idx >> 10;
    int s = u ^ ((u >> 3) & 7);
    int col = s >> 2;
    int g = s & 3;
    int k0 = kb * 32 + g * 8;
    const float* Wsrc = (col < 128) ? (Wmu + col) : (Wls + (col - 128));
    unsigned o[4];
#pragma unroll
    for (int p = 0; p < 4; ++p) {
        float lo = Wsrc[(size_t)(k0 + 2 * p) * 128];
        float hi = Wsrc[(size_t)(k0 + 2 * p + 1) * 128];
        o[p] = f2bf(lo) | (f2bf(hi) << 16);
    }
    uint4 v;
    v.x = o[0]; v.y = o[1]; v.z = o[2]; v.w = o[3];
    Wc[idx] = v;
}

// ---------------- MFMA GEMM: hs[N][256] = bf16(x @ [Wmu|Wls]) * dinv[row] ----------------
__global__ __launch_bounds__(256) void gemm_kernel(const float* __restrict__ x,
                                                   const uint4* __restrict__ Wc,
                                                   const float* __restrict__ dinv,
                                                   unsigned short* __restrict__ hs) {
    __shared__ __align__(16) unsigned short As[2][64 * 40];
    __shared__ __align__(16) unsigned short Bs[2][1024 * 8];

    int tid = threadIdx.x;
    int lane = tid & 63;
    int w = tid >> 6;
    int r0 = blockIdx.x * 64;

    int st_row = tid >> 2;
    int st_g = tid & 3;
    int xr = r0 + st_row;
    if (xr > NN - 1) xr = NN - 1;
    const float* xg = x + (size_t)xr * KC + st_g * 8;

    f32x4 acc[4][4];
    f32x4 zz = {0.f, 0.f, 0.f, 0.f};
#pragma unroll
    for (int a = 0; a < 4; ++a)
#pragma unroll
        for (int b = 0; b < 4; ++b) acc[a][b] = zz;

    float4 a0, a1;
    uint4 b0, b1, b2, b3;

    auto loadAB = [&](int kb) {
        a0 = *(const float4*)(xg + kb * 32);
        a1 = *(const float4*)(xg + kb * 32 + 4);
        const uint4* wsrc = Wc + kb * 1024 + tid;
        b0 = wsrc[0];
        b1 = wsrc[256];
        b2 = wsrc[512];
        b3 = wsrc[768];
    };
    auto storeAB = [&](int buf) {
        uint4 av;
        av.x = f2bf(a0.x) | (f2bf(a0.y) << 16);
        av.y = f2bf(a0.z) | (f2bf(a0.w) << 16);
        av.z = f2bf(a1.x) | (f2bf(a1.y) << 16);
        av.w = f2bf(a1.z) | (f2bf(a1.w) << 16);
        *(uint4*)&As[buf][st_row * 40 + st_g * 8] = av;
        uint4* bd = (uint4*)&Bs[buf][0];
        bd[tid] = b0;
        bd[tid + 256] = b1;
        bd[tid + 512] = b2;
        bd[tid + 768] = b3;
    };

    int i16 = lane & 15;
    int g4 = lane >> 4;

    loadAB(0);
    storeAB(0);
    __syncthreads();

#pragma unroll 2
    for (int kb = 0; kb < 16; ++kb) {
        int buf = kb & 1;
        if (kb < 15) loadAB(kb + 1);

        bf16x8 af[4];
#pragma unroll
        for (int fr = 0; fr < 4; ++fr)
            af[fr] = *(const bf16x8*)&As[buf][(fr * 16 + i16) * 40 + g4 * 8];
#pragma unroll
        for (int fc = 0; fc < 4; ++fc) {
            int scol = ((w * 64 + fc * 16 + i16) << 2) + g4;
            int u = scol ^ ((scol >> 3) & 7);
            bf16x8 bfrag = *(const bf16x8*)&Bs[buf][u * 8];
#pragma unroll
            for (int fr = 0; fr < 4; ++fr)
                acc[fr][fc] = __builtin_amdgcn_mfma_f32_16x16x32_bf16(af[fr], bfrag, acc[fr][fc], 0, 0, 0);
        }

        if (kb < 15) storeAB(buf ^ 1);
        __syncthreads();
    }

#pragma unroll
    for (int fr = 0; fr < 4; ++fr) {
#pragma unroll
        for (int r = 0; r < 4; ++r) {
            int gr = r0 + fr * 16 + g4 * 4 + r;
            if (gr < NN) {
                float dv = dinv[gr];
#pragma unroll
                for (int fc = 0; fc < 4; ++fc) {
                    int col = w * 64 + fc * 16 + i16;
                    hs[(size_t)gr * OC + col] = (unsigned short)f2bf(acc[fr][fc][r] * dv);
                }
            }
        }
    }
}

// ---------------- aggregation: out = dinv[n]*(sum_e hs[src] + hs[n]) + b ----------------
__global__ __launch_bounds__(256) void aggregate_kernel(const unsigned short* __restrict__ hs,
                                                        const int* __restrict__ row_start,
                                                        const int* __restrict__ csr_src,
                                                        const float* __restrict__ dinv,
                                                        const float* __restrict__ bmu,
                                                        const float* __restrict__ bls,
                                                        float* __restrict__ out) {
    int tid = threadIdx.x;
    int lane = tid & 63;
    int node = blockIdx.x * 4 + (tid >> 6);

    const unsigned short* hrow = hs + lane * 4;  // lane covers cols 4l..4l+3
    float acc0, acc1, acc2, acc3;
    {
        ushort4 v = *(const ushort4*)&hrow[(size_t)node * OC];
        acc0 = bf2f(v.x);
        acc1 = bf2f(v.y);
        acc2 = bf2f(v.z);
        acc3 = bf2f(v.w);
    }
    int rs = row_start[node], re = row_start[node + 1];
    int e = rs;
    for (; e + 1 < re; e += 2) {
        int s0 = csr_src[e], s1 = csr_src[e + 1];
        ushort4 v0 = *(const ushort4*)&hrow[(size_t)s0 * OC];
        ushort4 v1 = *(const ushort4*)&hrow[(size_t)s1 * OC];
        acc0 += bf2f(v0.x) + bf2f(v1.x);
        acc1 += bf2f(v0.y) + bf2f(v1.y);
        acc2 += bf2f(v0.z) + bf2f(v1.z);
        acc3 += bf2f(v0.w) + bf2f(v1.w);
    }
    if (e < re) {
        int s0 = csr_src[e];
        ushort4 v0 = *(const ushort4*)&hrow[(size_t)s0 * OC];
        acc0 += bf2f(v0.x);
        acc1 += bf2f(v0.y);
        acc2 += bf2f(v0.z);
        acc3 += bf2f(v0.w);
    }
    float dn = dinv[node];
    if (lane < 32) {
        float4 b = ((const float4*)bmu)[lane];
        float4 r = {acc0 * dn + b.x, acc1 * dn + b.y, acc2 * dn + b.z, acc3 * dn + b.w};
        ((float4*)out)[(size_t)node * 32 + lane] = r;
    } else {
        float4 b = ((const float4*)bls)[lane - 32];
        float4 r = {acc0 * dn + b.x, acc1 * dn + b.y, acc2 * dn + b.z, acc3 * dn + b.w};
        ((float4*)out)[(size_t)(NN + node) * 32 + (lane - 32)] = r;
    }
}

extern "C" void kernel_launch(void* const* d_in, const int* in_sizes, int n_in,
                              void* d_out, int out_size, void* d_ws, size_t ws_size,
                              hipStream_t stream) {
    const float* x = (const float*)d_in[0];
    const int* ei = (const int*)d_in[1];  // [2][NE]: src then dst
    const float* Wmu = (const float*)d_in[2];
    const float* bmu = (const float*)d_in[3];
    const float* Wls = (const float*)d_in[4];
    const float* bls = (const float*)d_in[5];
    float* out = (float*)d_out;

    char* ws = (char*)d_ws;
    size_t off = 0;
    auto alloc = [&](size_t bytes) {
        void* p = ws + off;
        off += (bytes + 255) & ~(size_t)255;
        return p;
    };
    unsigned short* hs = (unsigned short*)alloc((size_t)NN * OC * sizeof(unsigned short));  // 25.6 MB
    uint4* Wc = (uint4*)alloc((size_t)16384 * 16);                                          // 256 KB
    int* deg = (int*)alloc((size_t)NN * sizeof(int));
    int* row_start = (int*)alloc((size_t)(NN + 1) * sizeof(int));
    int* cursor = (int*)alloc((size_t)NN * sizeof(int));
    int* csr_src = (int*)alloc((size_t)NE * sizeof(int));
    float* dinv = (float*)alloc((size_t)NN * sizeof(float));
    int* partial = (int*)alloc((size_t)NB_SCAN * sizeof(int));
    int* blockoff = (int*)alloc((size_t)NB_SCAN * sizeof(int));

    hipMemsetAsync(deg, 0, (size_t)NN * sizeof(int), stream);

    count_deg_kernel<<<(NE + 255) / 256, 256, 0, stream>>>(ei, deg);
    scan_part_kernel<<<NB_SCAN, 256, 0, stream>>>(deg, partial);
    scan_block_kernel<<<1, 256, 0, stream>>>(partial, blockoff);
    scan_apply_kernel<<<NB_SCAN, 256, 0, stream>>>(deg, blockoff, row_start, cursor, dinv);
    scatter_kernel<<<(NE + 255) / 256, 256, 0, stream>>>(ei, cursor, csr_src);
    convw_kernel<<<64, 256, 0, stream>>>(Wmu, Wls, Wc);
    gemm_kernel<<<(NN + 63) / 64, 256, 0, stream>>>(x, Wc, dinv, hs);
    aggregate_kernel<<<NN / 4, 256, 0, stream>>>(hs, row_start, csr_src, dinv, bmu, bls, out);
}

// Round 4
// 198.860 us; speedup vs baseline: 2.7580x; 1.0890x over previous
//
#include <hip/hip_runtime.h>

#define NN 50000
#define NE 800000
#define KC 512
#define OC 256  // 128 mu cols | 128 logstd cols
#define NB_SCAN 196  // ceil(NN/256)

typedef float f32x4 __attribute__((ext_vector_type(4)));
typedef short bf16x8 __attribute__((ext_vector_type(8)));

__device__ __forceinline__ unsigned f2bf(float f) {
    union { float f; unsigned u; } v; v.f = f;
    return (v.u + 0x7FFFu + ((v.u >> 16) & 1u)) >> 16;  // RNE
}
__device__ __forceinline__ float bf2f(unsigned short b) {
    union { unsigned u; float f; } v; v.u = ((unsigned)b) << 16;
    return v.f;
}

// ---------------- degree count ----------------
__global__ __launch_bounds__(256) void count_deg_kernel(const int* __restrict__ ei,
                                                        int* __restrict__ deg) {
    int e = blockIdx.x * 256 + threadIdx.x;
    if (e < NE) atomicAdd(&deg[ei[NE + e]], 1);
}

// ---------------- hierarchical scan: A) per-block sums ----------------
__global__ __launch_bounds__(256) void scan_part_kernel(const int* __restrict__ deg,
                                                        int* __restrict__ partial) {
    int tid = threadIdx.x;
    int i = blockIdx.x * 256 + tid;
    int v = (i < NN) ? deg[i] : 0;
#pragma unroll
    for (int off = 32; off > 0; off >>= 1) v += __shfl_down(v, off, 64);
    __shared__ int wsum[4];
    if ((tid & 63) == 0) wsum[tid >> 6] = v;
    __syncthreads();
    if (tid == 0) partial[blockIdx.x] = wsum[0] + wsum[1] + wsum[2] + wsum[3];
}

// ---------------- B) scan the 196 partials (one tiny block) ----------------
__global__ __launch_bounds__(256) void scan_block_kernel(const int* __restrict__ partial,
                                                         int* __restrict__ blockoff) {
    __shared__ int lds[256];
    int tid = threadIdx.x;
    int v = (tid < NB_SCAN) ? partial[tid] : 0;
    lds[tid] = v;
    __syncthreads();
    for (int off = 1; off < 256; off <<= 1) {
        int t = (tid >= off) ? lds[tid - off] : 0;
        __syncthreads();
        lds[tid] += t;
        __syncthreads();
    }
    if (tid < NB_SCAN) blockoff[tid] = lds[tid] - v;  // exclusive
}

// ---------------- C) apply: block-local scan + offset, emit CSR ptrs + dinv ----------------
__global__ __launch_bounds__(256) void scan_apply_kernel(const int* __restrict__ deg,
                                                         const int* __restrict__ blockoff,
                                                         int* __restrict__ row_start,
                                                         int* __restrict__ cursor,
                                                         float* __restrict__ dinv) {
    int tid = threadIdx.x;
    int lane = tid & 63;
    int w = tid >> 6;
    int i = blockIdx.x * 256 + tid;
    int d = (i < NN) ? deg[i] : 0;
    int v = d;
#pragma unroll
    for (int off = 1; off < 64; off <<= 1) {
        int t = __shfl_up(v, off, 64);
        if (lane >= off) v += t;
    }
    __shared__ int wsum[4];
    if (lane == 63) wsum[w] = v;
    __syncthreads();
    int wof = 0;
    for (int k = 0; k < w; ++k) wof += wsum[k];
    int excl = blockoff[blockIdx.x] + wof + v - d;
    if (i < NN) {
        row_start[i] = excl;
        cursor[i] = excl;
        dinv[i] = rsqrtf((float)(d + 1));  // +1 self-loop
    }
    if (i == NN - 1) row_start[NN] = excl + d;
}

// ---------------- scatter edges into CSR (by dst) ----------------
__global__ __launch_bounds__(256) void scatter_kernel(const int* __restrict__ ei,
                                                      int* __restrict__ cursor,
                                                      int* __restrict__ csr_src) {
    int e = blockIdx.x * 256 + threadIdx.x;
    if (e < NE) {
        int d = ei[NE + e];
        int pos = atomicAdd(&cursor[d], 1);
        csr_src[pos] = ei[e];
    }
}

// ---------------- W -> fused bf16, fragment-slot-ordered + XOR-swizzled ----------------
__global__ __launch_bounds__(256) void convw_kernel(const float* __restrict__ Wmu,
                                                    const float* __restrict__ Wls,
                                                    uint4* __restrict__ Wc) {
    int idx = blockIdx.x * 256 + threadIdx.x;  // 16384 slots total
    int u = idx & 1023;
    int kb = idx >> 10;
    int s = u ^ ((u >> 3) & 7);
    int col = s >> 2;
    int g = s & 3;
    int k0 = kb * 32 + g * 8;
    const float* Wsrc = (col < 128) ? (Wmu + col) : (Wls + (col - 128));
    unsigned o[4];
#pragma unroll
    for (int p = 0; p < 4; ++p) {
        float lo = Wsrc[(size_t)(k0 + 2 * p) * 128];
        float hi = Wsrc[(size_t)(k0 + 2 * p + 1) * 128];
        o[p] = f2bf(lo) | (f2bf(hi) << 16);
    }
    uint4 v;
    v.x = o[0]; v.y = o[1]; v.z = o[2]; v.w = o[3];
    Wc[idx] = v;
}

// ---------------- MFMA GEMM: hs[N][256] = bf16(x @ [Wmu|Wls]) * dinv[row] ----------------
__global__ __launch_bounds__(256) void gemm_kernel(const float* __restrict__ x,
                                                   const uint4* __restrict__ Wc,
                                                   const float* __restrict__ dinv,
                                                   unsigned short* __restrict__ hs) {
    __shared__ __align__(16) unsigned short As[2][64 * 40];
    __shared__ __align__(16) unsigned short Bs[2][1024 * 8];

    int tid = threadIdx.x;
    int lane = tid & 63;
    int w = tid >> 6;
    int r0 = blockIdx.x * 64;

    int st_row = tid >> 2;
    int st_g = tid & 3;
    int xr = r0 + st_row;
    if (xr > NN - 1) xr = NN - 1;
    const float* xg = x + (size_t)xr * KC + st_g * 8;

    f32x4 acc[4][4];
    f32x4 zz = {0.f, 0.f, 0.f, 0.f};
#pragma unroll
    for (int a = 0; a < 4; ++a)
#pragma unroll
        for (int b = 0; b < 4; ++b) acc[a][b] = zz;

    float4 a0, a1;
    uint4 b0, b1, b2, b3;

    auto loadAB = [&](int kb) {
        a0 = *(const float4*)(xg + kb * 32);
        a1 = *(const float4*)(xg + kb * 32 + 4);
        const uint4* wsrc = Wc + kb * 1024 + tid;
        b0 = wsrc[0];
        b1 = wsrc[256];
        b2 = wsrc[512];
        b3 = wsrc[768];
    };
    auto storeAB = [&](int buf) {
        uint4 av;
        av.x = f2bf(a0.x) | (f2bf(a0.y) << 16);
        av.y = f2bf(a0.z) | (f2bf(a0.w) << 16);
        av.z = f2bf(a1.x) | (f2bf(a1.y) << 16);
        av.w = f2bf(a1.z) | (f2bf(a1.w) << 16);
        *(uint4*)&As[buf][st_row * 40 + st_g * 8] = av;
        uint4* bd = (uint4*)&Bs[buf][0];
        bd[tid] = b0;
        bd[tid + 256] = b1;
        bd[tid + 512] = b2;
        bd[tid + 768] = b3;
    };

    int i16 = lane & 15;
    int g4 = lane >> 4;

    loadAB(0);
    storeAB(0);
    __syncthreads();

#pragma unroll 2
    for (int kb = 0; kb < 16; ++kb) {
        int buf = kb & 1;
        if (kb < 15) loadAB(kb + 1);

        bf16x8 af[4];
#pragma unroll
        for (int fr = 0; fr < 4; ++fr)
            af[fr] = *(const bf16x8*)&As[buf][(fr * 16 + i16) * 40 + g4 * 8];
#pragma unroll
        for (int fc = 0; fc < 4; ++fc) {
            int scol = ((w * 64 + fc * 16 + i16) << 2) + g4;
            int u = scol ^ ((scol >> 3) & 7);
            bf16x8 bfrag = *(const bf16x8*)&Bs[buf][u * 8];
#pragma unroll
            for (int fr = 0; fr < 4; ++fr)
                acc[fr][fc] = __builtin_amdgcn_mfma_f32_16x16x32_bf16(af[fr], bfrag, acc[fr][fc], 0, 0, 0);
        }

        if (kb < 15) storeAB(buf ^ 1);
        __syncthreads();
    }

#pragma unroll
    for (int fr = 0; fr < 4; ++fr) {
#pragma unroll
        for (int r = 0; r < 4; ++r) {
            int gr = r0 + fr * 16 + g4 * 4 + r;
            if (gr < NN) {
                float dv = dinv[gr];
#pragma unroll
                for (int fc = 0; fc < 4; ++fc) {
                    int col = w * 64 + fc * 16 + i16;
                    hs[(size_t)gr * OC + col] = (unsigned short)f2bf(acc[fr][fc][r] * dv);
                }
            }
        }
    }
}

// ---------------- aggregation: out = dinv[n]*(sum_e hs[src] + hs[n]) + b ----------------
// 8-wide edge batches: issue 8 independent 512B row gathers per iteration (MLP).
__global__ __launch_bounds__(256) void aggregate_kernel(const unsigned short* __restrict__ hs,
                                                        const int* __restrict__ row_start,
                                                        const int* __restrict__ csr_src,
                                                        const float* __restrict__ dinv,
                                                        const float* __restrict__ bmu,
                                                        const float* __restrict__ bls,
                                                        float* __restrict__ out) {
    int tid = threadIdx.x;
    int lane = tid & 63;
    int node = blockIdx.x * 4 + (tid >> 6);

    const unsigned short* hrow = hs + lane * 4;  // lane covers cols 4l..4l+3
    float acc0, acc1, acc2, acc3;
    {
        ushort4 v = *(const ushort4*)&hrow[(size_t)node * OC];
        acc0 = bf2f(v.x);
        acc1 = bf2f(v.y);
        acc2 = bf2f(v.z);
        acc3 = bf2f(v.w);
    }
    int rs = row_start[node], re = row_start[node + 1];
    int e = rs;
    for (; e + 8 <= re; e += 8) {
        int s[8];
#pragma unroll
        for (int q = 0; q < 8; ++q) s[q] = csr_src[e + q];
        ushort4 v[8];
#pragma unroll
        for (int q = 0; q < 8; ++q) v[q] = *(const ushort4*)&hrow[(size_t)s[q] * OC];
#pragma unroll
        for (int q = 0; q < 8; ++q) {
            acc0 += bf2f(v[q].x);
            acc1 += bf2f(v[q].y);
            acc2 += bf2f(v[q].z);
            acc3 += bf2f(v[q].w);
        }
    }
    if (e + 4 <= re) {
        int s[4];
#pragma unroll
        for (int q = 0; q < 4; ++q) s[q] = csr_src[e + q];
        ushort4 v[4];
#pragma unroll
        for (int q = 0; q < 4; ++q) v[q] = *(const ushort4*)&hrow[(size_t)s[q] * OC];
#pragma unroll
        for (int q = 0; q < 4; ++q) {
            acc0 += bf2f(v[q].x);
            acc1 += bf2f(v[q].y);
            acc2 += bf2f(v[q].z);
            acc3 += bf2f(v[q].w);
        }
        e += 4;
    }
    for (; e < re; ++e) {
        int s0 = csr_src[e];
        ushort4 v0 = *(const ushort4*)&hrow[(size_t)s0 * OC];
        acc0 += bf2f(v0.x);
        acc1 += bf2f(v0.y);
        acc2 += bf2f(v0.z);
        acc3 += bf2f(v0.w);
    }
    float dn = dinv[node];
    if (lane < 32) {
        float4 b = ((const float4*)bmu)[lane];
        float4 r = {acc0 * dn + b.x, acc1 * dn + b.y, acc2 * dn + b.z, acc3 * dn + b.w};
        ((float4*)out)[(size_t)node * 32 + lane] = r;
    } else {
        float4 b = ((const float4*)bls)[lane - 32];
        float4 r = {acc0 * dn + b.x, acc1 * dn + b.y, acc2 * dn + b.z, acc3 * dn + b.w};
        ((float4*)out)[(size_t)(NN + node) * 32 + (lane - 32)] = r;
    }
}

extern "C" void kernel_launch(void* const* d_in, const int* in_sizes, int n_in,
                              void* d_out, int out_size, void* d_ws, size_t ws_size,
                              hipStream_t stream) {
    const float* x = (const float*)d_in[0];
    const int* ei = (const int*)d_in[1];  // [2][NE]: src then dst
    const float* Wmu = (const float*)d_in[2];
    const float* bmu = (const float*)d_in[3];
    const float* Wls = (const float*)d_in[4];
    const float* bls = (const float*)d_in[5];
    float* out = (float*)d_out;

    char* ws = (char*)d_ws;
    size_t off = 0;
    auto alloc = [&](size_t bytes) {
        void* p = ws + off;
        off += (bytes + 255) & ~(size_t)255;
        return p;
    };
    unsigned short* hs = (unsigned short*)alloc((size_t)NN * OC * sizeof(unsigned short));  // 25.6 MB
    uint4* Wc = (uint4*)alloc((size_t)16384 * 16);                                          // 256 KB
    int* deg = (int*)alloc((size_t)NN * sizeof(int));
    int* row_start = (int*)alloc((size_t)(NN + 1) * sizeof(int));
    int* cursor = (int*)alloc((size_t)NN * sizeof(int));
    int* csr_src = (int*)alloc((size_t)NE * sizeof(int));
    float* dinv = (float*)alloc((size_t)NN * sizeof(float));
    int* partial = (int*)alloc((size_t)NB_SCAN * sizeof(int));
    int* blockoff = (int*)alloc((size_t)NB_SCAN * sizeof(int));

    hipMemsetAsync(deg, 0, (size_t)NN * sizeof(int), stream);

    count_deg_kernel<<<(NE + 255) / 256, 256, 0, stream>>>(ei, deg);
    scan_part_kernel<<<NB_SCAN, 256, 0, stream>>>(deg, partial);
    scan_block_kernel<<<1, 256, 0, stream>>>(partial, blockoff);
    scan_apply_kernel<<<NB_SCAN, 256, 0, stream>>>(deg, blockoff, row_start, cursor, dinv);
    scatter_kernel<<<(NE + 255) / 256, 256, 0, stream>>>(ei, cursor, csr_src);
    convw_kernel<<<64, 256, 0, stream>>>(Wmu, Wls, Wc);
    gemm_kernel<<<(NN + 63) / 64, 256, 0, stream>>>(x, Wc, dinv, hs);
    aggregate_kernel<<<NN / 4, 256, 0, stream>>>(hs, row_start, csr_src, dinv, bmu, bls, out);
}